// Round 3
// baseline (725.646 us; speedup 1.0000x reference)
//
#include <hip/hip_runtime.h>

// MemoryReader: S = (2*K^T Q - |k|^2)/8, P = softmax_n(S), mem = V P ; out = [mem, qv]
// B=16, CK=64, CV=512, N=HW=3136 (pad to 3200)
//
// R3: TM=128 (halves per-batch V L2 traffic: 25 wgs/batch instead of 49, 2x MFMA
//     per V byte), split V prefetch (8 frags at iter top, 8 after barrier) to fit
//     256-reg budget, 64KB LDS P double-buffer with post-loop aliasing of the
//     reduction scratch, qv passthrough copy fused (software-pipelined) into the
//     main loop so its BW rides under compute.

#define B_   16
#define CK_  64
#define CV_  512
#define N_   3136
#define NPAD 3200
#define TM   128     // query tile per workgroup
#define TN   128     // memory tile per iteration
#define NITER 25     // 25*128 = 3200 covers padded N
#define NBLK32 100   // NPAD/32  (fragment blocks for K/Q)
#define NBLK16 200   // NPAD/16  (fragment blocks for V)

typedef __bf16 bf16_t;
typedef bf16_t bf16x8 __attribute__((ext_vector_type(8)));
typedef bf16_t bf16x4 __attribute__((ext_vector_type(4)));
typedef float  f32x16 __attribute__((ext_vector_type(16)));
typedef float  f32x4  __attribute__((ext_vector_type(4)));

#define SCALE_DOT 0.36067376022224085f  // 0.25 * log2(e) ; p = exp2((dot - 0.5|k|^2)*SCALE_DOT)

// ---- prep 1: K,Q -> fragment-ordered bf16, plus A2S[n] = 0.5*|k_n|^2 (pad -> 3e38)
__global__ __launch_bounds__(256) void prep_kq(const float* __restrict__ mk,
                                               const float* __restrict__ qk,
                                               bf16_t* __restrict__ Kf,
                                               bf16_t* __restrict__ Qf,
                                               float* __restrict__ a2) {
  int idx = blockIdx.x * 256 + threadIdx.x;       // 0 .. 16*3200-1 (grid exact)
  int b = idx / NPAD, n = idx % NPAD;
  bool valid = n < N_;
  int l32n = n & 31, nblk = n >> 5;
  float ss = 0.f;
  const float* mkp = mk + (size_t)b * CK_ * N_ + n;
  const float* qkp = qk + (size_t)b * CK_ * N_ + n;
  bf16x8* Kf8 = (bf16x8*)Kf;
  bf16x8* Qf8 = (bf16x8*)Qf;
  #pragma unroll
  for (int cc = 0; cc < 8; cc++) {                // c-chunk: c = 8*cc+j ; s = cc>>1, h = cc&1
    bf16x8 kv, qv8;
    #pragma unroll
    for (int j = 0; j < 8; j++) {
      int c = 8 * cc + j;
      float kx = valid ? mkp[(size_t)c * N_] : 0.f;
      float qx = valid ? qkp[(size_t)c * N_] : 0.f;
      ss += kx * kx;
      kv[j] = (bf16_t)kx;
      qv8[j] = (bf16_t)qx;
    }
    int s = cc >> 1, hh = cc & 1;
    size_t pos = (((size_t)b * NBLK32 + nblk) * 4 + s) * 64 + l32n + 32 * hh;
    Kf8[pos] = kv;
    Qf8[pos] = qv8;
  }
  // pad rows poisoned: exp2((0 - 3e38)*SCALE) == 0, so no bounds check in hot loop
  a2[idx] = valid ? ss * 0.5f : 3.0e38f;
}

// ---- prep 2: V -> fragment-ordered bf16 via LDS transpose (coalesced read+write)
//   Vf[b][cblk][nblk][lane][8]: lane holds V[cblk*32 + lane%32][nblk*16 + (lane/32)*8 + j]
#define VCHUNK 512
__global__ __launch_bounds__(256) void prep_v(const float* __restrict__ mv,
                                              bf16_t* __restrict__ Vf) {
  __shared__ __align__(16) bf16_t T[32][VCHUNK];  // 32KB, XOR-swizzled rows
  int wg = blockIdx.x;                            // 16*16*7 = 1792 wgs
  int chunk = wg % 7;
  int t2 = wg / 7;
  int cblk = t2 & 15;
  int b = t2 >> 4;
  int n0 = chunk * VCHUNK;
  int tid = threadIdx.x;

  const float* base = mv + ((size_t)b * CV_ + cblk * 32) * N_;
  #pragma unroll
  for (int rep = 0; rep < 16; rep++) {            // 32 rows x 512 f32 = 4096 f32x4
    int idx = rep * 256 + tid;
    int cl = idx >> 7;                            // 0..31
    int np = (idx & 127) * 4;                     // 0..508
    int n = n0 + np;
    bf16x4 o;
    if (n < N_) {                                 // N_ % 4 == 0: no straddle
      f32x4 v = *(const f32x4*)(base + (size_t)cl * N_ + n);
      #pragma unroll
      for (int j = 0; j < 4; j++) o[j] = (bf16_t)v[j];
    } else {
      #pragma unroll
      for (int j = 0; j < 4; j++) o[j] = (bf16_t)0.f;
    }
    *(bf16x4*)((char*)T + cl * (VCHUNK * 2) + ((np * 2) ^ ((cl & 7) << 4))) = o;
  }
  __syncthreads();

  bf16x8* Vf8 = (bf16x8*)Vf;
  size_t outbase = (((size_t)b * 16 + cblk) * NBLK16 + (n0 >> 4)) * 64;
  #pragma unroll
  for (int pass = 0; pass < 8; pass++) {          // 32 fragment chunks of 1KB
    int idx = pass * 256 + tid;
    int nb = idx >> 6;                            // local nblk 0..31
    int ln = idx & 63;
    if (n0 + nb * 16 < NPAD) {
      int cl = ln & 31;
      int n_loc = nb * 16 + (ln >> 5) * 8;
      bf16x8 o = *(bf16x8*)((char*)T + cl * (VCHUNK * 2) +
                            ((n_loc * 2) ^ ((cl & 7) << 4)));
      Vf8[outbase + (size_t)nb * 64 + ln] = o;
    }
  }
}

// ---- main fused kernel: one workgroup = (batch b, 128-query tile m0), 8 waves.
// S-phase: wave w computes n-block i=w&3 for m-blocks {2g, 2g+1} (g=w>>2), P to
//          swizzled LDS. O-phase: wave w owns channels [64w,64w+64) x 128 m,
//          acc[2][4]. qv passthrough fused into iters 0..16 (pipelined).
__global__ __launch_bounds__(512, 2) void attn_main(const bf16_t* __restrict__ Kf,
                                                    const bf16_t* __restrict__ Qf,
                                                    const float* __restrict__ A2S,
                                                    const bf16_t* __restrict__ Vf,
                                                    const float* __restrict__ qv,
                                                    float* __restrict__ out) {
  // XCD-pinned mapping: 400 wgs = 8 XCDs * (2 batches * 25 m-tiles)
  const int xcd = blockIdx.x & 7;
  const int idx = blockIdx.x >> 3;          // 0..49
  const int q25 = idx / 25;                 // 0..1
  const int b   = xcd * 2 + q25;
  const int m0  = (idx - q25 * 25) * TM;

  const int tid  = threadIdx.x;
  const int w    = tid >> 6;
  const int lane = tid & 63;
  const int l32  = lane & 31;
  const int h    = lane >> 5;
  const int g    = w >> 2;   // S-phase m-pair (0..1)
  const int i    = w & 3;    // S-phase n-slice (0..3)

  // 64KB pool: P double buffer [2][128 rows][256B]; reduction scratch aliases it
  __shared__ __align__(16) char pool[65536];

  const bf16x8* Qf8 = (const bf16x8*)Qf;
  bf16x8 qfrag[2][4];
  #pragma unroll
  for (int jj = 0; jj < 2; jj++)
    #pragma unroll
    for (int s = 0; s < 4; s++)
      qfrag[jj][s] = Qf8[(((size_t)b * NBLK32 + (m0 >> 5) + 2 * g + jj) * 4 + s) * 64 + lane];

  f32x16 acc[2][4];
  #pragma unroll
  for (int cb = 0; cb < 2; cb++)
    #pragma unroll
    for (int mb = 0; mb < 4; mb++)
      #pragma unroll
      for (int r = 0; r < 16; r++) acc[cb][mb][r] = 0.f;

  float Lp[2] = {0.f, 0.f};
  const float*  a2b = A2S + (size_t)b * NPAD;
  const bf16x8* Kf8 = (const bf16x8*)Kf;
  const bf16x8* Vf8 = (const bf16x8*)Vf + (((size_t)b * 16 + 2 * w) * NBLK16) * 64 + lane;

  const int rswz = (l32 & 15) << 4;         // P read swizzle (same for all 4 mb rows)

  // fused qv passthrough: 16 chunks of 1024 float4 per wg, pipelined load->store
  const f32x4* qsrc = (const f32x4*)qv;
  f32x4* qdst = (f32x4*)(out + (size_t)B_ * CV_ * N_);
  const size_t QT = (size_t)B_ * CV_ * N_ / 4;
  const size_t qbase = (size_t)blockIdx.x * 16384;
  f32x4 qr0, qr1;

  for (int iter = 0; iter < NITER; iter++) {
    const int n0 = iter * TN + 32 * i;

    // ---- store previous iter's qv chunk (data long since arrived) ----
    if (iter >= 1 && iter <= 16) {
      size_t qi = qbase + (size_t)(iter - 1) * 1024 + tid;
      if (qi < QT) qdst[qi] = qr0;
      if (qi + 512 < QT) qdst[qi + 512] = qr1;
    }

    // ---- issue K, a2, first half of V, and next qv chunk ----
    const bf16x8* kp = Kf8 + (((size_t)b * NBLK32 + (iter * 4 + i)) * 4) * 64 + lane;
    bf16x8 kf0 = kp[0], kf1 = kp[64], kf2 = kp[128], kf3 = kp[192];
    f32x4 na[4];
    #pragma unroll
    for (int t = 0; t < 4; t++)
      na[t] = *(const f32x4*)(a2b + n0 + 8 * t + 4 * h);
    const bf16x8* vp = Vf8 + (size_t)iter * 8 * 64;
    bf16x8 vfA[8];
    #pragma unroll
    for (int t = 0; t < 4; t++) {
      vfA[2 * t]     = vp[t * 64];
      vfA[2 * t + 1] = vp[t * 64 + NBLK16 * 64];
    }
    if (iter < 16) {
      size_t qi = qbase + (size_t)iter * 1024 + tid;
      if (qi < QT) qr0 = qsrc[qi];
      if (qi + 512 < QT) qr1 = qsrc[qi + 512];
    }

    // ---- S: two 32x32 tiles (m-blocks 2g, 2g+1), one sacc live at a time ----
    char* Pb = pool + (iter & 1) * 32768;
    #pragma unroll
    for (int jj = 0; jj < 2; jj++) {
      f32x16 sacc;
      #pragma unroll
      for (int t = 0; t < 4; t++)
        #pragma unroll
        for (int q = 0; q < 4; q++) sacc[4 * t + q] = -na[t][q];
      sacc = __builtin_amdgcn_mfma_f32_32x32x16_bf16(kf0, qfrag[jj][0], sacc, 0, 0, 0);
      sacc = __builtin_amdgcn_mfma_f32_32x32x16_bf16(kf1, qfrag[jj][1], sacc, 0, 0, 0);
      sacc = __builtin_amdgcn_mfma_f32_32x32x16_bf16(kf2, qfrag[jj][2], sacc, 0, 0, 0);
      sacc = __builtin_amdgcn_mfma_f32_32x32x16_bf16(kf3, qfrag[jj][3], sacc, 0, 0, 0);

      const int wrow = 32 * (2 * g + jj) + l32;
      const int wswz = (l32 & 15) << 4;     // wrow & 15 == l32 & 15
      #pragma unroll
      for (int t = 0; t < 4; t++) {
        bf16x4 pk;
        #pragma unroll
        for (int q = 0; q < 4; q++) {
          float p = __builtin_amdgcn_exp2f(sacc[4 * t + q] * SCALE_DOT);
          Lp[jj] += p;
          pk[q] = (bf16_t)p;
        }
        int colb = 64 * i + 16 * t + 8 * h;
        *(bf16x4*)(Pb + wrow * 256 + (colb ^ wswz)) = pk;
      }
    }

    // ---- raw barrier: drain LDS only; global loads stay in flight ----
    asm volatile("s_waitcnt lgkmcnt(0)" ::: "memory");
    __builtin_amdgcn_s_barrier();

    // ---- issue second half of V (latency covered by first 32 MFMA) ----
    bf16x8 vfB[8];
    #pragma unroll
    for (int t = 0; t < 4; t++) {
      vfB[2 * t]     = vp[(t + 4) * 64];
      vfB[2 * t + 1] = vp[(t + 4) * 64 + NBLK16 * 64];
    }

    // ---- O: acc[cb][mb] += V[.][k] * P[k][.] ----
    #pragma unroll
    for (int t = 0; t < 8; t++) {
      bf16x8 va0 = (t < 4) ? vfA[2 * t]     : vfB[2 * (t - 4)];
      bf16x8 va1 = (t < 4) ? vfA[2 * t + 1] : vfB[2 * (t - 4) + 1];
      #pragma unroll
      for (int mb = 0; mb < 4; mb++) {
        bf16x8 pf = *(const bf16x8*)(Pb + (32 * mb + l32) * 256 + ((32 * t + 16 * h) ^ rswz));
        acc[0][mb] = __builtin_amdgcn_mfma_f32_32x32x16_bf16(va0, pf, acc[0][mb], 0, 0, 0);
        acc[1][mb] = __builtin_amdgcn_mfma_f32_32x32x16_bf16(va1, pf, acc[1][mb], 0, 0, 0);
      }
    }
    // double buffer: next iter writes pool[buf^1]; the single barrier per iter
    // orders read(buf)@i against write(buf)@i+2.
  }

  // ---- column-sum (softmax denominator) reduction; scratch aliases pool ----
  __syncthreads();                          // all P reads complete before overwrite
  Lp[0] += __shfl_xor(Lp[0], 32, 64);
  Lp[1] += __shfl_xor(Lp[1], 32, 64);
  float* Llds = (float*)pool;               // [8][2][32]
  float* Linv = (float*)(pool + 2048);      // [128]
  if (h == 0) {
    Llds[(w * 2 + 0) * 32 + l32] = Lp[0];
    Llds[(w * 2 + 1) * 32 + l32] = Lp[1];
  }
  __syncthreads();
  if (tid < 128) {
    int mb = tid >> 5, l = tid & 31;
    int g2 = mb >> 1, jj = mb & 1;
    float s = 0.f;
    #pragma unroll
    for (int ww = 0; ww < 4; ww++) s += Llds[((4 * g2 + ww) * 2 + jj) * 32 + l];
    Linv[tid] = 1.0f / s;
  }
  __syncthreads();

  // ---- epilogue: normalize + store fp32 (guard padded m) ----
  #pragma unroll
  for (int cb = 0; cb < 2; cb++) {
    #pragma unroll
    for (int mb = 0; mb < 4; mb++) {
      int m = m0 + 32 * mb + l32;
      if (m < N_) {
        float rl = Linv[32 * mb + l32];
        #pragma unroll
        for (int reg = 0; reg < 16; reg++) {
          int r = (reg & 3) + 8 * (reg >> 2) + 4 * h;
          int c = 64 * w + 32 * cb + r;
          out[((size_t)b * CV_ + c) * N_ + m] = acc[cb][mb][reg] * rl;
        }
      }
    }
  }
}

extern "C" void kernel_launch(void* const* d_in, const int* in_sizes, int n_in,
                              void* d_out, int out_size, void* d_ws, size_t ws_size,
                              hipStream_t stream) {
  const float* mk = (const float*)d_in[0];
  const float* qk = (const float*)d_in[1];
  const float* mv = (const float*)d_in[2];
  const float* qv = (const float*)d_in[3];
  float* out = (float*)d_out;

  // workspace layout (bytes):
  //   Kf  [16][100][4][64][8] bf16 : 6,553,600   @ 0
  //   Qf  [16][100][4][64][8] bf16 : 6,553,600   @ 6,553,600
  //   A2S [16][3200]     f32       :   204,800   @ 13,107,200
  //   Vf  [16][16][200][64][8]bf16 : 52,428,800  @ 13,312,000
  char* ws = (char*)d_ws;
  bf16_t* Kf = (bf16_t*)(ws);
  bf16_t* Qf = (bf16_t*)(ws + 6553600);
  float*  a2 = (float*)(ws + 13107200);
  bf16_t* Vf = (bf16_t*)(ws + 13312000);

  prep_kq<<<dim3((B_ * NPAD) / 256), dim3(256), 0, stream>>>(mk, qk, Kf, Qf, a2);
  prep_v<<<dim3(B_ * 16 * 7), dim3(256), 0, stream>>>(mv, Vf);
  attn_main<<<dim3(B_ * 25), dim3(512), 0, stream>>>(Kf, Qf, a2, Vf, qv, out);
}

// Round 5
// 686.202 us; speedup vs baseline: 1.0575x; 1.0575x over previous
//
#include <hip/hip_runtime.h>

// MemoryReader: S = (2*K^T Q - |k|^2)/8, P = softmax_n(S), mem = V P ; out = [mem, qv]
// B=16, CK=64, CV=512, N=HW=3136 (pad to 3200)
//
// R5 == R4 resubmitted (R4 bench was an infra failure, no measurement):
//     TM=128 with the R3 register spill fixed:
//     - vfA issued AFTER S-MFMAs (covered by exp/pack/barrier, not held through S)
//     - qv chunk loaded at iter top, stored before the barrier (dead during O)
//     - S-phase jj=0/1 MFMA chains interleaved (both saccs live, no dep bubbles)
//     - preps fused into one kernel (one less launch boundary)
//     Peak live regs ~236 < 256 cap of __launch_bounds__(512,2).

#define B_   16
#define CK_  64
#define CV_  512
#define N_   3136
#define NPAD 3200
#define TM   128     // query tile per workgroup
#define TN   128     // memory tile per iteration
#define NITER 25     // 25*128 = 3200 covers padded N
#define NBLK32 100   // NPAD/32  (fragment blocks for K/Q)
#define NBLK16 200   // NPAD/16  (fragment blocks for V)

typedef __bf16 bf16_t;
typedef bf16_t bf16x8 __attribute__((ext_vector_type(8)));
typedef bf16_t bf16x4 __attribute__((ext_vector_type(4)));
typedef float  f32x16 __attribute__((ext_vector_type(16)));
typedef float  f32x4  __attribute__((ext_vector_type(4)));

#define SCALE_DOT 0.36067376022224085f  // 0.25 * log2(e) ; p = exp2((dot - 0.5|k|^2)*SCALE_DOT)
#define VCHUNK 512

// ---- fused prep: wgs [0,200) do K/Q fragment transpose + |k|^2;
//                  wgs [200,1992) do V fragment transpose via LDS.
__global__ __launch_bounds__(256) void prep_all(const float* __restrict__ mk,
                                                const float* __restrict__ qk,
                                                const float* __restrict__ mv,
                                                bf16_t* __restrict__ Kf,
                                                bf16_t* __restrict__ Qf,
                                                float* __restrict__ a2,
                                                bf16_t* __restrict__ Vf) {
  __shared__ __align__(16) bf16_t T[32][VCHUNK];  // 32KB (used by V part only)
  int wg = blockIdx.x;
  int tid = threadIdx.x;

  if (wg < 200) {
    // ---- K/Q part: fragment layout Kf[b][nblk][s][lane][8],
    //      lane = (n%32) + 32*h holds K[nblk*32+n%32][16s+8h+j]
    int idx = wg * 256 + tid;                     // 0 .. 16*3200-1
    int b = idx / NPAD, n = idx % NPAD;
    bool valid = n < N_;
    int l32n = n & 31, nblk = n >> 5;
    float ss = 0.f;
    const float* mkp = mk + (size_t)b * CK_ * N_ + n;
    const float* qkp = qk + (size_t)b * CK_ * N_ + n;
    bf16x8* Kf8 = (bf16x8*)Kf;
    bf16x8* Qf8 = (bf16x8*)Qf;
    #pragma unroll
    for (int cc = 0; cc < 8; cc++) {              // c = 8*cc+j ; s = cc>>1, h = cc&1
      bf16x8 kv, qv8;
      #pragma unroll
      for (int j = 0; j < 8; j++) {
        int c = 8 * cc + j;
        float kx = valid ? mkp[(size_t)c * N_] : 0.f;
        float qx = valid ? qkp[(size_t)c * N_] : 0.f;
        ss += kx * kx;
        kv[j] = (bf16_t)kx;
        qv8[j] = (bf16_t)qx;
      }
      int s = cc >> 1, hh = cc & 1;
      size_t pos = (((size_t)b * NBLK32 + nblk) * 4 + s) * 64 + l32n + 32 * hh;
      Kf8[pos] = kv;
      Qf8[pos] = qv8;
    }
    // pad rows poisoned: exp2((0 - 3e38)*SCALE) == 0 -> no bounds check in hot loop
    a2[idx] = valid ? ss * 0.5f : 3.0e38f;
  } else {
    // ---- V part: Vf[b][cblk][nblk][lane][8],
    //      lane holds V[cblk*32 + lane%32][nblk*16 + (lane/32)*8 + j]
    int wg2 = wg - 200;                           // 0 .. 1791
    int chunk = wg2 % 7;
    int t2 = wg2 / 7;
    int cblk = t2 & 15;
    int b = t2 >> 4;
    int n0 = chunk * VCHUNK;

    const float* base = mv + ((size_t)b * CV_ + cblk * 32) * N_;
    #pragma unroll
    for (int rep = 0; rep < 16; rep++) {          // 32 rows x 512 f32
      int idx = rep * 256 + tid;
      int cl = idx >> 7;                          // 0..31
      int np = (idx & 127) * 4;                   // 0..508
      int n = n0 + np;
      bf16x4 o;
      if (n < N_) {                               // N_ % 4 == 0: no straddle
        f32x4 v = *(const f32x4*)(base + (size_t)cl * N_ + n);
        #pragma unroll
        for (int j = 0; j < 4; j++) o[j] = (bf16_t)v[j];
      } else {
        #pragma unroll
        for (int j = 0; j < 4; j++) o[j] = (bf16_t)0.f;
      }
      *(bf16x4*)((char*)T + cl * (VCHUNK * 2) + ((np * 2) ^ ((cl & 7) << 4))) = o;
    }
    __syncthreads();

    bf16x8* Vf8 = (bf16x8*)Vf;
    size_t outbase = (((size_t)b * 16 + cblk) * NBLK16 + (n0 >> 4)) * 64;
    #pragma unroll
    for (int pass = 0; pass < 8; pass++) {        // 32 fragment chunks of 1KB
      int idx = pass * 256 + tid;
      int nb = idx >> 6;                          // local nblk 0..31
      int ln = idx & 63;
      if (n0 + nb * 16 < NPAD) {
        int cl = ln & 31;
        int n_loc = nb * 16 + (ln >> 5) * 8;
        bf16x8 o = *(bf16x8*)((char*)T + cl * (VCHUNK * 2) +
                              ((n_loc * 2) ^ ((cl & 7) << 4)));
        Vf8[outbase + (size_t)nb * 64 + ln] = o;
      }
    }
  }
}

// ---- main fused kernel: one workgroup = (batch b, 128-query tile m0), 8 waves.
// S-phase: wave w computes n-block i=w&3 for m-blocks {2g,2g+1} (g=w>>2), both
//          MFMA chains interleaved; P -> swizzled LDS.
// O-phase: wave w owns channels [64w,64w+64) x 128 m, acc[2][4]; V prefetch
//          split vfA (pre-barrier, covered by exp) / vfB (post-barrier, covered
//          by first-half MFMAs). qv passthrough pipelined within each iter.
__global__ __launch_bounds__(512, 2) void attn_main(const bf16_t* __restrict__ Kf,
                                                    const bf16_t* __restrict__ Qf,
                                                    const float* __restrict__ A2S,
                                                    const bf16_t* __restrict__ Vf,
                                                    const float* __restrict__ qv,
                                                    float* __restrict__ out) {
  // XCD-pinned mapping: 400 wgs = 8 XCDs * (2 batches * 25 m-tiles)
  const int xcd = blockIdx.x & 7;
  const int idx = blockIdx.x >> 3;          // 0..49
  const int q25 = idx / 25;                 // 0..1
  const int b   = xcd * 2 + q25;
  const int m0  = (idx - q25 * 25) * TM;

  const int tid  = threadIdx.x;
  const int w    = tid >> 6;
  const int lane = tid & 63;
  const int l32  = lane & 31;
  const int h    = lane >> 5;
  const int g    = w >> 2;   // S-phase m-pair (0..1)
  const int i    = w & 3;    // S-phase n-slice (0..3)

  // 64KB pool: P double buffer [2][128 rows][256B]; reduction scratch aliases it
  __shared__ __align__(16) char pool[65536];

  const bf16x8* Qf8 = (const bf16x8*)Qf;
  bf16x8 qfrag[2][4];
  #pragma unroll
  for (int jj = 0; jj < 2; jj++)
    #pragma unroll
    for (int s = 0; s < 4; s++)
      qfrag[jj][s] = Qf8[(((size_t)b * NBLK32 + (m0 >> 5) + 2 * g + jj) * 4 + s) * 64 + lane];

  f32x16 acc[2][4];
  #pragma unroll
  for (int cb = 0; cb < 2; cb++)
    #pragma unroll
    for (int mb = 0; mb < 4; mb++)
      #pragma unroll
      for (int r = 0; r < 16; r++) acc[cb][mb][r] = 0.f;

  float Lp[2] = {0.f, 0.f};
  const float*  a2b = A2S + (size_t)b * NPAD;
  const bf16x8* Kf8 = (const bf16x8*)Kf;
  const bf16x8* Vf8 = (const bf16x8*)Vf + (((size_t)b * 16 + 2 * w) * NBLK16) * 64 + lane;

  const int rswz = (l32 & 15) << 4;         // P read swizzle (same for all mb rows)

  // fused qv passthrough: 16 chunks of 1024 float4 per wg, load+store same iter
  const f32x4* qsrc = (const f32x4*)qv;
  f32x4* qdst = (f32x4*)(out + (size_t)B_ * CV_ * N_);
  const size_t QT = (size_t)B_ * CV_ * N_ / 4;
  const size_t qbase = (size_t)blockIdx.x * 16384;

  for (int iter = 0; iter < NITER; iter++) {
    const int n0 = iter * TN + 32 * i;

    // ---- issue K, a2, qv chunk ----
    const bf16x8* kp = Kf8 + (((size_t)b * NBLK32 + (iter * 4 + i)) * 4) * 64 + lane;
    bf16x8 kfr[4];
    kfr[0] = kp[0]; kfr[1] = kp[64]; kfr[2] = kp[128]; kfr[3] = kp[192];
    f32x4 na[4];
    #pragma unroll
    for (int t = 0; t < 4; t++)
      na[t] = *(const f32x4*)(a2b + n0 + 8 * t + 4 * h);
    f32x4 qr0, qr1;
    const bool qval = iter < 16;
    const size_t qi = qbase + (size_t)iter * 1024 + tid;
    if (qval) {
      if (qi < QT) qr0 = qsrc[qi];
      if (qi + 512 < QT) qr1 = qsrc[qi + 512];
    }

    // ---- S: both 32x32 m-tiles, chains interleaved (no dep bubbles) ----
    f32x16 sc[2];
    #pragma unroll
    for (int jj = 0; jj < 2; jj++)
      #pragma unroll
      for (int t = 0; t < 4; t++)
        #pragma unroll
        for (int q = 0; q < 4; q++) sc[jj][4 * t + q] = -na[t][q];
    #pragma unroll
    for (int s = 0; s < 4; s++) {
      sc[0] = __builtin_amdgcn_mfma_f32_32x32x16_bf16(kfr[s], qfrag[0][s], sc[0], 0, 0, 0);
      sc[1] = __builtin_amdgcn_mfma_f32_32x32x16_bf16(kfr[s], qfrag[1][s], sc[1], 0, 0, 0);
    }
    __builtin_amdgcn_sched_barrier(0);  // keep vfA issue here, not hoisted above S

    // ---- issue first half of V (latency covered by exp/pack + barrier) ----
    const bf16x8* vp = Vf8 + (size_t)iter * 8 * 64;
    bf16x8 vfA[8];
    #pragma unroll
    for (int t = 0; t < 4; t++) {
      vfA[2 * t]     = vp[t * 64];
      vfA[2 * t + 1] = vp[t * 64 + NBLK16 * 64];
    }

    // ---- P = exp2(s*SCALE); pack bf16 -> swizzled LDS; column sums ----
    char* Pb = pool + (iter & 1) * 32768;
    #pragma unroll
    for (int jj = 0; jj < 2; jj++) {
      const int wrow = 32 * (2 * g + jj) + l32;
      const int wswz = (l32 & 15) << 4;         // wrow&15 == l32&15
      #pragma unroll
      for (int t = 0; t < 4; t++) {
        bf16x4 pk;
        #pragma unroll
        for (int q = 0; q < 4; q++) {
          float p = __builtin_amdgcn_exp2f(sc[jj][4 * t + q] * SCALE_DOT);
          Lp[jj] += p;
          pk[q] = (bf16_t)p;
        }
        int colb = 64 * i + 16 * t + 8 * h;
        *(bf16x4*)(Pb + wrow * 256 + (colb ^ wswz)) = pk;
      }
    }

    // ---- qv store (qr dies before the register-peak O-phase) ----
    if (qval) {
      if (qi < QT) qdst[qi] = qr0;
      if (qi + 512 < QT) qdst[qi + 512] = qr1;
    }

    // ---- raw barrier: drain LDS only; V loads stay in flight ----
    asm volatile("s_waitcnt lgkmcnt(0)" ::: "memory");
    __builtin_amdgcn_s_barrier();

    // ---- issue second half of V (covered by first-half MFMAs) ----
    bf16x8 vfB[8];
    #pragma unroll
    for (int t = 0; t < 4; t++) {
      vfB[2 * t]     = vp[(t + 4) * 64];
      vfB[2 * t + 1] = vp[(t + 4) * 64 + NBLK16 * 64];
    }

    // ---- O: acc[cb][mb] += V[.][k] * P[k][.] ----
    #pragma unroll
    for (int t = 0; t < 8; t++) {
      bf16x8 va0 = (t < 4) ? vfA[2 * t]     : vfB[2 * (t - 4)];
      bf16x8 va1 = (t < 4) ? vfA[2 * t + 1] : vfB[2 * (t - 4) + 1];
      #pragma unroll
      for (int mb = 0; mb < 4; mb++) {
        bf16x8 pf = *(const bf16x8*)(Pb + (32 * mb + l32) * 256 + ((32 * t + 16 * h) ^ rswz));
        acc[0][mb] = __builtin_amdgcn_mfma_f32_32x32x16_bf16(va0, pf, acc[0][mb], 0, 0, 0);
        acc[1][mb] = __builtin_amdgcn_mfma_f32_32x32x16_bf16(va1, pf, acc[1][mb], 0, 0, 0);
      }
    }
    // double buffer: next iter writes pool[buf^1]; the single barrier per iter
    // orders read(buf)@i against write(buf)@i+2.
  }

  // ---- column-sum (softmax denominator) reduction; scratch aliases pool ----
  __syncthreads();                          // all P reads complete before overwrite
  Lp[0] += __shfl_xor(Lp[0], 32, 64);
  Lp[1] += __shfl_xor(Lp[1], 32, 64);
  float* Llds = (float*)pool;               // [8][2][32]
  float* Linv = (float*)(pool + 2048);      // [128]
  if (h == 0) {
    Llds[(w * 2 + 0) * 32 + l32] = Lp[0];
    Llds[(w * 2 + 1) * 32 + l32] = Lp[1];
  }
  __syncthreads();
  if (tid < 128) {
    int mb = tid >> 5, l = tid & 31;
    int g2 = mb >> 1, jj = mb & 1;
    float s = 0.f;
    #pragma unroll
    for (int ww = 0; ww < 4; ww++) s += Llds[((4 * g2 + ww) * 2 + jj) * 32 + l];
    Linv[tid] = 1.0f / s;
  }
  __syncthreads();

  // ---- epilogue: normalize + store fp32 (guard padded m) ----
  #pragma unroll
  for (int cb = 0; cb < 2; cb++) {
    #pragma unroll
    for (int mb = 0; mb < 4; mb++) {
      int m = m0 + 32 * mb + l32;
      if (m < N_) {
        float rl = Linv[32 * mb + l32];
        #pragma unroll
        for (int reg = 0; reg < 16; reg++) {
          int r = (reg & 3) + 8 * (reg >> 2) + 4 * h;
          int c = 64 * w + 32 * cb + r;
          out[((size_t)b * CV_ + c) * N_ + m] = acc[cb][mb][reg] * rl;
        }
      }
    }
  }
}

extern "C" void kernel_launch(void* const* d_in, const int* in_sizes, int n_in,
                              void* d_out, int out_size, void* d_ws, size_t ws_size,
                              hipStream_t stream) {
  const float* mk = (const float*)d_in[0];
  const float* qk = (const float*)d_in[1];
  const float* mv = (const float*)d_in[2];
  const float* qv = (const float*)d_in[3];
  float* out = (float*)d_out;

  // workspace layout (bytes):
  //   Kf  [16][100][4][64][8] bf16 : 6,553,600   @ 0
  //   Qf  [16][100][4][64][8] bf16 : 6,553,600   @ 6,553,600
  //   A2S [16][3200]     f32       :   204,800   @ 13,107,200
  //   Vf  [16][16][200][64][8]bf16 : 52,428,800  @ 13,312,000
  char* ws = (char*)d_ws;
  bf16_t* Kf = (bf16_t*)(ws);
  bf16_t* Qf = (bf16_t*)(ws + 6553600);
  float*  a2 = (float*)(ws + 13107200);
  bf16_t* Vf = (bf16_t*)(ws + 13312000);

  prep_all<<<dim3(200 + B_ * 16 * 7), dim3(256), 0, stream>>>(mk, qk, mv, Kf, Qf, a2, Vf);
  attn_main<<<dim3(B_ * 25), dim3(512), 0, stream>>>(Kf, Qf, a2, Vf, qv, out);
}